// Round 8
// baseline (210.513 us; speedup 1.0000x reference)
//
#include <hip/hip_runtime.h>

// YOLO v1 loss, B=16384, S=7, C=30. 192.7 MB read -> 1 float.
// Layout: pred[((b*S+i)*S+j)*30 + c]; i -> gi (x offset), j -> gj (y offset).
//
// v7: v6 refuted the MLP theory (120 KB/CU in flight, same 70 us). Last
// untested structural difference vs the 6.3 TB/s m13 copy probe: one-shot
// burst+drain vs PERSISTENT STEADY STREAM. This version: 512 persistent
// blocks (2/CU resident), each owns a contiguous ~6-tile range; pred tiles
// double-buffered in LDS via global_load_lds (stage t+1 while computing t);
// targ read as plain float2 reg loads issued BEFORE staging so the vmcnt
// FIFO wait for targ leaves staging in flight. One vmcnt(0)+barrier per
// tile at the end of compute; machine never fully drains. lsum accumulated
// across tiles, one reduce at kernel end, partials to workspace.
// Decision rule: <55 us => stream-shape was the cap; 63-75 us => ~2.7 TB/s
// is the genuine uncore ceiling -> ROOFLINE.

#define NS 7
#define NC 30
#define BLOCK 256
#define GRIDP 512                 // persistent blocks: 2 per CU, all resident
#define NT 3136                   // tiles of 256 cells
#define TILE_FLOATS 7680          // 256 cells * 30 floats = 30720 B

typedef const __attribute__((address_space(1))) unsigned int* gas_ptr;
typedef __attribute__((address_space(3))) unsigned int* las_ptr;

__device__ __forceinline__ void async_cp16(const float* g, float* l) {
    // 16-byte direct global->LDS, no VGPR destination (validated in v6).
    __builtin_amdgcn_global_load_lds((gas_ptr)g, (las_ptr)l, 16, 0, 0);
}

__device__ __forceinline__ void stage_tile(const float* __restrict__ gbase,
                                           float* lbase, int tid) {
    // 30720 B = 1920 x 16B chunks: 7 full rounds of 256 threads + 128-chunk
    // tail (wave-uniform: waves 0,1 all-on, waves 2,3 all-off).
    #pragma unroll
    for (int k = 0; k < 7; ++k) {
        int cid = k * BLOCK + tid;
        async_cp16(gbase + (size_t)cid * 4, lbase + cid * 4);
    }
    if (tid < 128) {
        int cid = 7 * BLOCK + tid;
        async_cp16(gbase + (size_t)cid * 4, lbase + cid * 4);
    }
}

__global__ void zero_out_kernel(float* out) { out[0] = 0.0f; }

__global__ __launch_bounds__(BLOCK) void yolo_loss_kernel(
    const float* __restrict__ pred,
    const float* __restrict__ targ,
    float* __restrict__ partial,
    float* __restrict__ out,
    int atomic_mode, float inv_B)
{
    const float STEP = 1.0f / 7.0f;
    const float L_COORD = 5.0f;
    const float L_NOOBJ = 0.5f;

    __shared__ float sbuf[2][TILE_FLOATS];   // 61440 B double buffer

    const int tid = threadIdx.x;
    const int b = blockIdx.x;
    // Balanced contiguous tile ranges: 6 or 7 tiles per block.
    const int tstart = (int)(((long long)b * NT) / GRIDP);
    const int tend   = (int)(((long long)(b + 1) * NT) / GRIDP);

    float lsum = 0.0f;
    int c = 0;

    stage_tile(pred + (size_t)tstart * TILE_FLOATS, sbuf[0], tid);
    asm volatile("s_waitcnt vmcnt(0)" ::: "memory");
    __syncthreads();

    for (int t = tstart; t < tend; ++t) {
        const int cell = t * BLOCK + tid;

        // ---- targ loads to regs, issued FIRST (oldest in vmcnt FIFO) ----
        const float2* t2 = (const float2*)targ + (size_t)cell * 15;
        float tt[NC];
        #pragma unroll
        for (int k = 0; k < 15; ++k) {
            float2 u = t2[k];
            tt[2 * k] = u.x; tt[2 * k + 1] = u.y;
        }

        // ---- stage NEXT tile's pred into the other buffer (stays in flight
        //      across this iteration's compute; drained at loop bottom) ----
        if (t + 1 < tend)
            stage_tile(pred + (size_t)(t + 1) * TILE_FLOATS, sbuf[c ^ 1], tid);

        // ---- own cell's pred from LDS ----
        float p[NC];
        {
            const float2* s2 = (const float2*)(&sbuf[c][0]) + tid * 15;
            #pragma unroll
            for (int k = 0; k < 15; ++k) {
                float2 v = s2[k];
                p[2 * k] = v.x; p[2 * k + 1] = v.y;
            }
        }

        // ---- loss, arithmetic identical to v0..v6 (absmax 0) ----
        int j = cell % NS;            // second spatial axis -> gj
        int i = (cell / NS) % NS;     // first spatial axis  -> gi
        float gi = (float)i;
        float gj = (float)j;

        float ta, tb, tc, td;
        {
            float cx = (tt[0] + gi) * STEP;
            float cy = (tt[1] + gj) * STEP;
            ta = fmaxf(cx - tt[2] * 0.5f, 0.0f);
            tb = fmaxf(cy - tt[3] * 0.5f, 0.0f);
            tc = fminf(cx + tt[2] * 0.5f, 1.0f);
            td = fminf(cy + tt[3] * 0.5f, 1.0f);
        }
        float q1, w1, e1, r1;
        {
            float cx = (p[0] + gi) * STEP;
            float cy = (p[1] + gj) * STEP;
            q1 = fmaxf(cx - p[2] * 0.5f, 0.0f);
            w1 = fmaxf(cy - p[3] * 0.5f, 0.0f);
            e1 = fminf(cx + p[2] * 0.5f, 1.0f);
            r1 = fminf(cy + p[3] * 0.5f, 1.0f);
        }
        float q2, w2, e2, r2;
        {
            float cx = (p[5] + gi) * STEP;
            float cy = (p[6] + gj) * STEP;
            q2 = fmaxf(cx - p[7] * 0.5f, 0.0f);
            w2 = fmaxf(cy - p[8] * 0.5f, 0.0f);
            e2 = fminf(cx + p[7] * 0.5f, 1.0f);
            r2 = fminf(cy + p[8] * 0.5f, 1.0f);
        }

        float tarea = (td - tb) * (tc - ta);
        float iou1, iou2;
        {
            float minx = fmaxf(ta, q1), miny = fmaxf(tb, w1);
            float maxx = fminf(tc, e1), maxy = fminf(td, r1);
            float inter = (maxy - miny) * (maxx - minx);
            float uni = (e1 - q1) * (r1 - w1) + tarea - inter;
            iou1 = (inter > 0.0f) ? inter / (uni + 1e-5f) : 0.0f;
        }
        {
            float minx = fmaxf(ta, q2), miny = fmaxf(tb, w2);
            float maxx = fminf(tc, e2), maxy = fminf(td, r2);
            float inter = (maxy - miny) * (maxx - minx);
            float uni = (e2 - q2) * (r2 - w2) + tarea - inter;
            iou2 = (inter > 0.0f) ? inter / (uni + 1e-5f) : 0.0f;
        }

        bool sel2 = (iou1 <= iou2);
        float conf_t = sel2 ? iou2 : iou1;
        float px = sel2 ? p[5] : p[0];
        float py = sel2 ? p[6] : p[1];
        float pw = sel2 ? p[7] : p[2];
        float ph = sel2 ? p[8] : p[3];
        float pconf = sel2 ? p[9] : p[4];

        float obj = (tt[4] > 0.0f) ? 1.0f : 0.0f;
        float noobj = (tt[4] == 0.0f) ? 1.0f : 0.0f;

        float dx = px - tt[0], dy = py - tt[1];
        float dw = pw - tt[2], dh = ph - tt[3];
        float coord = dx * dx + dy * dy + dw * dw + dh * dh;

        float dc = pconf - conf_t;
        float obj_loss = dc * dc;

        float cls = 0.0f;
        #pragma unroll
        for (int k = 10; k < NC; ++k) {
            float d = p[k] - tt[k];
            cls += d * d;
        }

        float d4 = p[4] - tt[4];
        float d9 = p[9] - tt[9];
        float noobj_loss = d4 * d4 + d9 * d9;

        lsum += obj * (obj_loss + L_COORD * coord + cls) + L_NOOBJ * noobj * noobj_loss;

        // ---- drain this iteration's staging, swap buffers ----
        asm volatile("s_waitcnt vmcnt(0)" ::: "memory");
        __syncthreads();
        c ^= 1;
    }

    // wave(64) shuffle reduce of the per-thread multi-tile sum
    #pragma unroll
    for (int off = 32; off > 0; off >>= 1)
        lsum += __shfl_down(lsum, off, 64);

    __shared__ float wsum[4];
    int lane = tid & 63;
    int wid = tid >> 6;
    if (lane == 0) wsum[wid] = lsum;
    __syncthreads();
    if (tid == 0) {
        float s = (wsum[0] + wsum[1]) + (wsum[2] + wsum[3]);
        if (atomic_mode) atomicAdd(out, s * inv_B);
        else partial[blockIdx.x] = s;
    }
}

__global__ __launch_bounds__(BLOCK) void reduce_kernel(
    const float* __restrict__ partial, float* __restrict__ out,
    int n, float inv_B)
{
    const int tid = threadIdx.x;
    float s = 0.0f;
    for (int idx = tid; idx < n; idx += BLOCK) s += partial[idx];

    #pragma unroll
    for (int off = 32; off > 0; off >>= 1)
        s += __shfl_down(s, off, 64);

    __shared__ float wsum[4];
    int lane = tid & 63;
    int wid = tid >> 6;
    if (lane == 0) wsum[wid] = s;
    __syncthreads();
    if (tid == 0)
        out[0] = ((wsum[0] + wsum[1]) + (wsum[2] + wsum[3])) * inv_B;
}

extern "C" void kernel_launch(void* const* d_in, const int* in_sizes, int n_in,
                              void* d_out, int out_size, void* d_ws, size_t ws_size,
                              hipStream_t stream) {
    const float* pred = (const float*)d_in[0];
    const float* targ = (const float*)d_in[1];
    float* out = (float*)d_out;

    const int B = 16384;
    const float inv_B = 1.0f / (float)B;

    if (ws_size >= (size_t)GRIDP * sizeof(float) && d_ws != nullptr) {
        float* partial = (float*)d_ws;
        yolo_loss_kernel<<<GRIDP, BLOCK, 0, stream>>>(pred, targ, partial, out, 0, inv_B);
        reduce_kernel<<<1, BLOCK, 0, stream>>>(partial, out, GRIDP, inv_B);
    } else {
        zero_out_kernel<<<1, 1, 0, stream>>>(out);
        yolo_loss_kernel<<<GRIDP, BLOCK, 0, stream>>>(pred, targ, nullptr, out, 1, inv_B);
    }
}